// Round 2
// baseline (934.320 us; speedup 1.0000x reference)
//
#include <hip/hip_runtime.h>
#include <hip/hip_bf16.h>

#define IN_CH   256
#define NOUT    128      // HEADS*OUT_CH
#define OUT_CH  64
#define NEG     0.2f

typedef __attribute__((ext_vector_type(8))) short bf16x8;   // 8 bf16 = 4 VGPRs
typedef __attribute__((ext_vector_type(4))) float f32x4;

static __device__ __forceinline__ short f2bf(float f) {
    __hip_bfloat16 h = __float2bfloat16(f);
    return *reinterpret_cast<short*>(&h);
}

// ---------- Wt[n][k] = bf16(W[k][n])  (W: 256x128 f32) ----------
__global__ void k_transpose_w(const float* __restrict__ W,
                              __hip_bfloat16* __restrict__ Wt) {
    int i = blockIdx.x * blockDim.x + threadIdx.x;
    if (i < IN_CH * NOUT) {
        int n = i >> 8, k = i & 255;
        Wt[i] = __float2bfloat16(W[k * NOUT + n]);
    }
}

// ---------- x = bf16(z) @ bf16(W) via mfma_f32_16x16x32_bf16, one wave = 16 rows x 128 cols ----------
// A layout: lane holds A[m=lane&15][k=quad*8+j]
// B layout: lane holds B[k=quad*8+j][n=lane&15] -> contiguous read from Wt[n][k]
// C/D: col=lane&15, row=quad*4+reg
__global__ __launch_bounds__(256) void k_gemm_x(
        const float* __restrict__ z,
        const __hip_bfloat16* __restrict__ wt,
        __hip_bfloat16* __restrict__ x, int nTiles) {
    int wid  = (blockIdx.x * blockDim.x + threadIdx.x) >> 6;
    if (wid >= nTiles) return;
    int lane = threadIdx.x & 63;
    int m = lane & 15, quad = lane >> 4;
    int rbase = wid * 16;
    const float* zp = z + (size_t)(rbase + m) * IN_CH + quad * 8;
    const short* wp = (const short*)wt + m * IN_CH + quad * 8;
    f32x4 acc[8] = {};
#pragma unroll
    for (int kb = 0; kb < 8; ++kb) {
        float4 f0 = *(const float4*)(zp + kb * 32);
        float4 f1 = *(const float4*)(zp + kb * 32 + 4);
        bf16x8 a;
        a[0] = f2bf(f0.x); a[1] = f2bf(f0.y); a[2] = f2bf(f0.z); a[3] = f2bf(f0.w);
        a[4] = f2bf(f1.x); a[5] = f2bf(f1.y); a[6] = f2bf(f1.z); a[7] = f2bf(f1.w);
#pragma unroll
        for (int n = 0; n < 8; ++n) {
            bf16x8 b = *(const bf16x8*)(wp + n * 16 * IN_CH + kb * 32);
            acc[n] = __builtin_amdgcn_mfma_f32_16x16x32_bf16(a, b, acc[n], 0, 0, 0);
        }
    }
#pragma unroll
    for (int n = 0; n < 8; ++n)
#pragma unroll
        for (int r = 0; r < 4; ++r) {
            int row = rbase + quad * 4 + r;
            x[(size_t)row * NOUT + n * 16 + m] = __float2bfloat16(acc[n][r]);
        }
}

// ---------- a_src[v][h] = dot(x[v,h,:], att_src[h,:]) ; same for a_dst. one wave/node ----------
__global__ __launch_bounds__(256) void k_att_scores(
        const __hip_bfloat16* __restrict__ x,
        const float* __restrict__ att_s,
        const float* __restrict__ att_d,
        float* __restrict__ a_src, float* __restrict__ a_dst, int N) {
    int wid  = (blockIdx.x * blockDim.x + threadIdx.x) >> 6;
    if (wid >= N) return;
    int lane = threadIdx.x & 63;
    __hip_bfloat162 f = ((const __hip_bfloat162*)(x + (size_t)wid * NOUT))[lane];
    float2 as = ((const float2*)att_s)[lane];
    float2 ad = ((const float2*)att_d)[lane];
    float fx = __bfloat162float(f.x), fy = __bfloat162float(f.y);
    float ps = fx * as.x + fy * as.y;
    float pd = fx * ad.x + fy * ad.y;
    // reduce within each 32-lane half (head 0 = lanes 0..31, head 1 = lanes 32..63)
    for (int msk = 1; msk < 32; msk <<= 1) {
        ps += __shfl_xor(ps, msk);
        pd += __shfl_xor(pd, msk);
    }
    if (lane == 0)  { a_src[2 * wid + 0] = ps; a_dst[2 * wid + 0] = pd; }
    if (lane == 32) { a_src[2 * wid + 1] = ps; a_dst[2 * wid + 1] = pd; }
}

// ---------- CSR build ----------
__global__ void k_init_deg(int* __restrict__ deg, int N) {
    int i = blockIdx.x * blockDim.x + threadIdx.x;
    if (i < N) deg[i] = 1;  // self loop
}

__global__ void k_hist(const int* __restrict__ ei, int* __restrict__ deg, int E) {
    int e = blockIdx.x * blockDim.x + threadIdx.x;
    if (e < E) atomicAdd(&deg[ei[E + e]], 1);
}

// block scans 2048 elements (256 thr x 8 items)
__global__ __launch_bounds__(256) void k_scan1(const int* __restrict__ deg,
                                               int* __restrict__ offs,
                                               int* __restrict__ bsum, int N) {
    __shared__ int sd[256];
    int t = threadIdx.x, b = blockIdx.x;
    int base = b * 2048 + t * 8;
    int it[8], s = 0;
#pragma unroll
    for (int j = 0; j < 8; ++j) {
        int idx = base + j;
        it[j] = (idx < N) ? deg[idx] : 0;
        s += it[j];
    }
    sd[t] = s;
    __syncthreads();
    for (int off = 1; off < 256; off <<= 1) {
        int v = (t >= off) ? sd[t - off] : 0;
        __syncthreads();
        sd[t] += v;
        __syncthreads();
    }
    int excl = sd[t] - s;
    if (t == 255) bsum[b] = sd[255];
    int run = excl;
#pragma unroll
    for (int j = 0; j < 8; ++j) {
        int idx = base + j;
        if (idx < N) offs[idx] = run;
        run += it[j];
    }
}

__global__ void k_scan2(int* __restrict__ bsum, int* __restrict__ offs, int NB, int N) {
    int t = threadIdx.x;  // 64 threads
    int v = (t < NB) ? bsum[t] : 0;
    int orig = v;
    for (int off = 1; off < 64; off <<= 1) {
        int u = __shfl_up(v, off);
        if (t >= off) v += u;
    }
    if (t < NB) bsum[t] = v - orig;       // exclusive block offset
    if (t == 63) offs[N] = v;             // grand total = E + N
}

__global__ void k_scan3(int* __restrict__ offs, int* __restrict__ wptr,
                        const int* __restrict__ bsum, int N) {
    int i = blockIdx.x * blockDim.x + threadIdx.x;
    if (i < N) {
        int o = offs[i] + bsum[i >> 11];
        offs[i] = o;
        wptr[i] = o;
    }
}

__global__ void k_scatter(const int* __restrict__ ei, int* __restrict__ wptr,
                          int* __restrict__ esrc, int E, int N) {
    int e = blockIdx.x * blockDim.x + threadIdx.x;
    if (e < E + N) {
        int s, d;
        if (e < E) { s = ei[e]; d = ei[E + e]; }
        else       { s = d = e - E; }
        int pos = atomicAdd(&wptr[d], 1);
        esrc[pos] = s;
    }
}

// ---------- main GAT aggregation: one wave per destination node ----------
__global__ __launch_bounds__(256) void k_gat_agg(
        const int* __restrict__ esrc, const int* __restrict__ offs,
        const float* __restrict__ a_src, const float* __restrict__ a_dst,
        const __hip_bfloat16* __restrict__ x, const float* __restrict__ bias,
        float* __restrict__ out, int N) {
    int wid  = (blockIdx.x * blockDim.x + threadIdx.x) >> 6;
    if (wid >= N) return;
    int lane = threadIdx.x & 63;
    int beg = offs[wid], end = offs[wid + 1];
    float2 ad = ((const float2*)a_dst)[wid];

    // pass 1: softmax denominator per head (no max-subtract: logits ~ N(0,2), safe in f32)
    float s0 = 0.f, s1 = 0.f;
    for (int i = beg + lane; i < end; i += 64) {
        int s = esrc[i];
        float2 as = ((const float2*)a_src)[s];
        float l0 = as.x + ad.x; l0 = (l0 > 0.f) ? l0 : NEG * l0;
        float l1 = as.y + ad.y; l1 = (l1 > 0.f) ? l1 : NEG * l1;
        s0 += __expf(l0);
        s1 += __expf(l1);
    }
    for (int msk = 1; msk < 64; msk <<= 1) {
        s0 += __shfl_xor(s0, msk);
        s1 += __shfl_xor(s1, msk);
    }
    int  h    = lane >> 5;                 // lanes 0..31 -> head 0 cols, 32..63 -> head 1
    float adh = h ? ad.y : ad.x;
    float inv = h ? (1.f / s1) : (1.f / s0);

    // pass 2: weighted feature accumulation; lane owns x-row bf162 element `lane`
    float acc0 = 0.f, acc1 = 0.f;
    const __hip_bfloat162* xv = (const __hip_bfloat162*)x;
    for (int i = beg; i < end; ++i) {
        int s = esrc[i];                                   // uniform across wave
        float2 as = ((const float2*)a_src)[s];
        float l = (h ? as.y : as.x) + adh;
        l = (l > 0.f) ? l : NEG * l;
        float alpha = __expf(l) * inv;
        __hip_bfloat162 f = xv[(size_t)s * 64 + lane];
        acc0 += alpha * __bfloat162float(f.x);
        acc1 += alpha * __bfloat162float(f.y);
    }
    // mean over heads: lane L<32 has head0 chans {2L,2L+1}; lane L+32 has head1 same chans
    float o0 = acc0 + __shfl_xor(acc0, 32);
    float o1 = acc1 + __shfl_xor(acc1, 32);
    if (lane < 32) {
        int c = 2 * lane;
        float2 o;
        o.x = 0.5f * o0 + bias[c];
        o.y = 0.5f * o1 + bias[c + 1];
        ((float2*)out)[(size_t)wid * 32 + lane] = o;
    }
}

extern "C" void kernel_launch(void* const* d_in, const int* in_sizes, int n_in,
                              void* d_out, int out_size, void* d_ws, size_t ws_size,
                              hipStream_t stream) {
    const float* z     = (const float*)d_in[0];
    const int*   ei    = (const int*)d_in[1];
    const float* W     = (const float*)d_in[2];
    const float* att_s = (const float*)d_in[3];
    const float* att_d = (const float*)d_in[4];
    const float* bias  = (const float*)d_in[5];
    float* out = (float*)d_out;

    const int N = in_sizes[0] / IN_CH;     // 100000
    const int E = in_sizes[1] / 2;         // 3200000
    const int Etot = E + N;

    // workspace carve-up (256B aligned)
    size_t off = 0;
    auto alloc = [&](size_t bytes) {
        void* p = (char*)d_ws + off;
        off += (bytes + 255) & ~(size_t)255;
        return p;
    };
    __hip_bfloat16* x    = (__hip_bfloat16*)alloc((size_t)N * NOUT * 2);
    __hip_bfloat16* Wt   = (__hip_bfloat16*)alloc((size_t)IN_CH * NOUT * 2);
    float* a_src         = (float*)alloc((size_t)N * 2 * 4);
    float* a_dst         = (float*)alloc((size_t)N * 2 * 4);
    int*   deg           = (int*)alloc((size_t)N * 4);
    int*   offs          = (int*)alloc((size_t)(N + 1) * 4);
    int*   wptr          = (int*)alloc((size_t)N * 4);
    int*   bsum          = (int*)alloc(64 * 4);
    int*   esrc          = (int*)alloc((size_t)Etot * 4);
    (void)ws_size;

    const int nTiles = N / 16;                 // 6250
    const int NB     = (N + 2047) / 2048;      // 49

    k_transpose_w<<<(IN_CH * NOUT + 255) / 256, 256, 0, stream>>>(W, Wt);
    k_gemm_x<<<(nTiles + 3) / 4, 256, 0, stream>>>(z, Wt, x, nTiles);
    k_att_scores<<<(N + 3) / 4, 256, 0, stream>>>(x, att_s, att_d, a_src, a_dst, N);
    k_init_deg<<<(N + 255) / 256, 256, 0, stream>>>(deg, N);
    k_hist<<<(E + 255) / 256, 256, 0, stream>>>(ei, deg, E);
    k_scan1<<<NB, 256, 0, stream>>>(deg, offs, bsum, N);
    k_scan2<<<1, 64, 0, stream>>>(bsum, offs, NB, N);
    k_scan3<<<(N + 255) / 256, 256, 0, stream>>>(offs, wptr, bsum, N);
    k_scatter<<<(Etot + 255) / 256, 256, 0, stream>>>(ei, wptr, esrc, E, N);
    k_gat_agg<<<(N + 3) / 4, 256, 0, stream>>>(esrc, offs, a_src, a_dst, x, bias, out, N);
}

// Round 3
// 695.121 us; speedup vs baseline: 1.3441x; 1.3441x over previous
//
#include <hip/hip_runtime.h>
#include <hip/hip_bf16.h>

#define IN_CH   256
#define NOUT    128      // HEADS*OUT_CH
#define OUT_CH  64
#define NEG     0.2f

typedef __attribute__((ext_vector_type(8))) short bf16x8;   // 8 bf16 = 4 VGPRs
typedef __attribute__((ext_vector_type(4))) float f32x4;

static __device__ __forceinline__ short f2bf(float f) {
    __hip_bfloat16 h = __float2bfloat16(f);
    return *reinterpret_cast<short*>(&h);
}

// ---------- Wt[n][k] = bf16(W[k][n])  (W: 256x128 f32) ----------
__global__ void k_transpose_w(const float* __restrict__ W,
                              __hip_bfloat16* __restrict__ Wt) {
    int i = blockIdx.x * blockDim.x + threadIdx.x;
    if (i < IN_CH * NOUT) {
        int n = i >> 8, k = i & 255;
        Wt[i] = __float2bfloat16(W[k * NOUT + n]);
    }
}

// ---------- x = bf16(z) @ bf16(W) via mfma_f32_16x16x32_bf16, one wave = 16 rows x 128 cols ----------
// A layout: lane holds A[m=lane&15][k=quad*8+j]
// B layout: lane holds B[k=quad*8+j][n=lane&15] -> contiguous read from Wt[n][k]
// C/D: col=lane&15, row=quad*4+reg
__global__ __launch_bounds__(256) void k_gemm_x(
        const float* __restrict__ z,
        const __hip_bfloat16* __restrict__ wt,
        __hip_bfloat16* __restrict__ x, int nTiles) {
    int wid  = (blockIdx.x * blockDim.x + threadIdx.x) >> 6;
    if (wid >= nTiles) return;
    int lane = threadIdx.x & 63;
    int m = lane & 15, quad = lane >> 4;
    int rbase = wid * 16;
    const float* zp = z + (size_t)(rbase + m) * IN_CH + quad * 8;
    const short* wp = (const short*)wt + m * IN_CH + quad * 8;
    f32x4 acc[8] = {};
#pragma unroll
    for (int kb = 0; kb < 8; ++kb) {
        float4 f0 = *(const float4*)(zp + kb * 32);
        float4 f1 = *(const float4*)(zp + kb * 32 + 4);
        bf16x8 a;
        a[0] = f2bf(f0.x); a[1] = f2bf(f0.y); a[2] = f2bf(f0.z); a[3] = f2bf(f0.w);
        a[4] = f2bf(f1.x); a[5] = f2bf(f1.y); a[6] = f2bf(f1.z); a[7] = f2bf(f1.w);
#pragma unroll
        for (int n = 0; n < 8; ++n) {
            bf16x8 b = *(const bf16x8*)(wp + n * 16 * IN_CH + kb * 32);
            acc[n] = __builtin_amdgcn_mfma_f32_16x16x32_bf16(a, b, acc[n], 0, 0, 0);
        }
    }
#pragma unroll
    for (int n = 0; n < 8; ++n)
#pragma unroll
        for (int r = 0; r < 4; ++r) {
            int row = rbase + quad * 4 + r;
            x[(size_t)row * NOUT + n * 16 + m] = __float2bfloat16(acc[n][r]);
        }
}

// ---------- a_src[v][h] = dot(x[v,h,:], att_src[h,:]) ; same for a_dst. one wave/node ----------
__global__ __launch_bounds__(256) void k_att_scores(
        const __hip_bfloat16* __restrict__ x,
        const float* __restrict__ att_s,
        const float* __restrict__ att_d,
        float* __restrict__ a_src, float* __restrict__ a_dst, int N) {
    int wid  = (blockIdx.x * blockDim.x + threadIdx.x) >> 6;
    if (wid >= N) return;
    int lane = threadIdx.x & 63;
    __hip_bfloat162 f = ((const __hip_bfloat162*)(x + (size_t)wid * NOUT))[lane];
    float2 as = ((const float2*)att_s)[lane];
    float2 ad = ((const float2*)att_d)[lane];
    float fx = __bfloat162float(f.x), fy = __bfloat162float(f.y);
    float ps = fx * as.x + fy * as.y;
    float pd = fx * ad.x + fy * ad.y;
    // reduce within each 32-lane half (head 0 = lanes 0..31, head 1 = lanes 32..63)
    for (int msk = 1; msk < 32; msk <<= 1) {
        ps += __shfl_xor(ps, msk);
        pd += __shfl_xor(pd, msk);
    }
    if (lane == 0)  { a_src[2 * wid + 0] = ps; a_dst[2 * wid + 0] = pd; }
    if (lane == 32) { a_src[2 * wid + 1] = ps; a_dst[2 * wid + 1] = pd; }
}

// ---------- CSR build ----------
__global__ void k_init_deg(int* __restrict__ deg, int N) {
    int i = blockIdx.x * blockDim.x + threadIdx.x;
    if (i < N) deg[i] = 1;  // self loop
}

__global__ void k_hist(const int* __restrict__ ei, int* __restrict__ deg, int E) {
    int e = blockIdx.x * blockDim.x + threadIdx.x;
    if (e < E) atomicAdd(&deg[ei[E + e]], 1);
}

// block scans 2048 elements (256 thr x 8 items)
__global__ __launch_bounds__(256) void k_scan1(const int* __restrict__ deg,
                                               int* __restrict__ offs,
                                               int* __restrict__ bsum, int N) {
    __shared__ int sd[256];
    int t = threadIdx.x, b = blockIdx.x;
    int base = b * 2048 + t * 8;
    int it[8], s = 0;
#pragma unroll
    for (int j = 0; j < 8; ++j) {
        int idx = base + j;
        it[j] = (idx < N) ? deg[idx] : 0;
        s += it[j];
    }
    sd[t] = s;
    __syncthreads();
    for (int off = 1; off < 256; off <<= 1) {
        int v = (t >= off) ? sd[t - off] : 0;
        __syncthreads();
        sd[t] += v;
        __syncthreads();
    }
    int excl = sd[t] - s;
    if (t == 255) bsum[b] = sd[255];
    int run = excl;
#pragma unroll
    for (int j = 0; j < 8; ++j) {
        int idx = base + j;
        if (idx < N) offs[idx] = run;
        run += it[j];
    }
}

__global__ void k_scan2(int* __restrict__ bsum, int* __restrict__ offs, int NB, int N) {
    int t = threadIdx.x;  // 64 threads
    int v = (t < NB) ? bsum[t] : 0;
    int orig = v;
    for (int off = 1; off < 64; off <<= 1) {
        int u = __shfl_up(v, off);
        if (t >= off) v += u;
    }
    if (t < NB) bsum[t] = v - orig;       // exclusive block offset
    if (t == 63) offs[N] = v;             // grand total = E + N
}

__global__ void k_scan3(int* __restrict__ offs, int* __restrict__ wptr,
                        const int* __restrict__ bsum, int N) {
    int i = blockIdx.x * blockDim.x + threadIdx.x;
    if (i < N) {
        int o = offs[i] + bsum[i >> 11];
        offs[i] = o;
        wptr[i] = o;
    }
}

// ---------- scatter + per-edge exp precompute: epk[pos] = {e_h0, e_h1, src} ----------
__global__ void k_scatter(const int* __restrict__ ei, int* __restrict__ wptr,
                          const float* __restrict__ a_src, const float* __restrict__ a_dst,
                          float4* __restrict__ epk, int E, int N) {
    int e = blockIdx.x * blockDim.x + threadIdx.x;
    if (e < E + N) {
        int s, d;
        if (e < E) { s = ei[e]; d = ei[E + e]; }
        else       { s = d = e - E; }
        float2 as = ((const float2*)a_src)[s];
        float2 ad = ((const float2*)a_dst)[d];
        float l0 = as.x + ad.x; l0 = (l0 > 0.f) ? l0 : NEG * l0;
        float l1 = as.y + ad.y; l1 = (l1 > 0.f) ? l1 : NEG * l1;
        int pos = atomicAdd(&wptr[d], 1);
        epk[pos] = make_float4(__expf(l0), __expf(l1), __int_as_float(s), 0.f);
    }
}

// ---------- main GAT aggregation: one wave per dst node, single fused pass ----------
// out_h = (sum_i e_i x_i) / (sum_i e_i)  -- unnormalized accumulate, divide once.
__global__ __launch_bounds__(256) void k_gat_agg(
        const float4* __restrict__ epk, const int* __restrict__ offs,
        const __hip_bfloat16* __restrict__ x, const float* __restrict__ bias,
        float* __restrict__ out, int N) {
    int wid  = (blockIdx.x * blockDim.x + threadIdx.x) >> 6;
    if (wid >= N) return;
    int lane = threadIdx.x & 63;
    int beg = offs[wid], end = offs[wid + 1];
    int h = lane >> 5;   // lanes 0..31: head0 chans, 32..63: head1 chans
    const __hip_bfloat162* xv = (const __hip_bfloat162*)x;

    float ax0 = 0.f, ay0 = 0.f, dn0 = 0.f;   // dual accumulators (break FMA chains,
    float ax1 = 0.f, ay1 = 0.f, dn1 = 0.f;   //  2 gathers in flight per iter)
    int i = beg;
    for (; i + 1 < end; i += 2) {
        float4 p0 = epk[i];
        float4 p1 = epk[i + 1];
        int s0 = __float_as_int(p0.z);
        int s1 = __float_as_int(p1.z);
        __hip_bfloat162 f0 = xv[(size_t)s0 * 64 + lane];
        __hip_bfloat162 f1 = xv[(size_t)s1 * 64 + lane];
        float e0 = h ? p0.y : p0.x;
        float e1 = h ? p1.y : p1.x;
        ax0 += e0 * __bfloat162float(f0.x);
        ay0 += e0 * __bfloat162float(f0.y);
        dn0 += e0;
        ax1 += e1 * __bfloat162float(f1.x);
        ay1 += e1 * __bfloat162float(f1.y);
        dn1 += e1;
    }
    if (i < end) {
        float4 p0 = epk[i];
        int s0 = __float_as_int(p0.z);
        __hip_bfloat162 f0 = xv[(size_t)s0 * 64 + lane];
        float e0 = h ? p0.y : p0.x;
        ax0 += e0 * __bfloat162float(f0.x);
        ay0 += e0 * __bfloat162float(f0.y);
        dn0 += e0;
    }
    float inv = 1.f / (dn0 + dn1);
    float accx = (ax0 + ax1) * inv;
    float accy = (ay0 + ay1) * inv;
    // mean over heads: lane L<32 has head0 chans {2L,2L+1}; lane L+32 has head1 same chans
    float o0 = accx + __shfl_xor(accx, 32);
    float o1 = accy + __shfl_xor(accy, 32);
    if (lane < 32) {
        int c = 2 * lane;
        float2 o;
        o.x = 0.5f * o0 + bias[c];
        o.y = 0.5f * o1 + bias[c + 1];
        ((float2*)out)[(size_t)wid * 32 + lane] = o;
    }
}

extern "C" void kernel_launch(void* const* d_in, const int* in_sizes, int n_in,
                              void* d_out, int out_size, void* d_ws, size_t ws_size,
                              hipStream_t stream) {
    const float* z     = (const float*)d_in[0];
    const int*   ei    = (const int*)d_in[1];
    const float* W     = (const float*)d_in[2];
    const float* att_s = (const float*)d_in[3];
    const float* att_d = (const float*)d_in[4];
    const float* bias  = (const float*)d_in[5];
    float* out = (float*)d_out;

    const int N = in_sizes[0] / IN_CH;     // 100000
    const int E = in_sizes[1] / 2;         // 3200000
    const int Etot = E + N;

    // workspace carve-up (256B aligned)
    size_t off = 0;
    auto alloc = [&](size_t bytes) {
        void* p = (char*)d_ws + off;
        off += (bytes + 255) & ~(size_t)255;
        return p;
    };
    __hip_bfloat16* x    = (__hip_bfloat16*)alloc((size_t)N * NOUT * 2);
    __hip_bfloat16* Wt   = (__hip_bfloat16*)alloc((size_t)IN_CH * NOUT * 2);
    float* a_src         = (float*)alloc((size_t)N * 2 * 4);
    float* a_dst         = (float*)alloc((size_t)N * 2 * 4);
    int*   deg           = (int*)alloc((size_t)N * 4);
    int*   offs          = (int*)alloc((size_t)(N + 1) * 4);
    int*   wptr          = (int*)alloc((size_t)N * 4);
    int*   bsum          = (int*)alloc(64 * 4);
    float4* epk          = (float4*)alloc((size_t)Etot * 16);
    (void)ws_size;

    const int nTiles = N / 16;                 // 6250
    const int NB     = (N + 2047) / 2048;      // 49

    k_transpose_w<<<(IN_CH * NOUT + 255) / 256, 256, 0, stream>>>(W, Wt);
    k_gemm_x<<<(nTiles + 3) / 4, 256, 0, stream>>>(z, Wt, x, nTiles);
    k_att_scores<<<(N + 3) / 4, 256, 0, stream>>>(x, att_s, att_d, a_src, a_dst, N);
    k_init_deg<<<(N + 255) / 256, 256, 0, stream>>>(deg, N);
    k_hist<<<(E + 255) / 256, 256, 0, stream>>>(ei, deg, E);
    k_scan1<<<NB, 256, 0, stream>>>(deg, offs, bsum, N);
    k_scan2<<<1, 64, 0, stream>>>(bsum, offs, NB, N);
    k_scan3<<<(N + 255) / 256, 256, 0, stream>>>(offs, wptr, bsum, N);
    k_scatter<<<(Etot + 255) / 256, 256, 0, stream>>>(ei, wptr, a_src, a_dst, epk, E, N);
    k_gat_agg<<<(N + 3) / 4, 256, 0, stream>>>(epk, offs, x, bias, out, N);
}

// Round 4
// 525.280 us; speedup vs baseline: 1.7787x; 1.3233x over previous
//
#include <hip/hip_runtime.h>
#include <hip/hip_bf16.h>
#include <hip/hip_fp16.h>

#define IN_CH   256
#define NOUT    128      // HEADS*OUT_CH
#define OUT_CH  64
#define NEG     0.2f

typedef __attribute__((ext_vector_type(8))) short bf16x8;   // 8 bf16 = 4 VGPRs
typedef __attribute__((ext_vector_type(4))) float f32x4;

static __device__ __forceinline__ short f2bf(float f) {
    __hip_bfloat16 h = __float2bfloat16(f);
    return *reinterpret_cast<short*>(&h);
}

// ---------- Wt[n][k] = bf16(W[k][n])  (W: 256x128 f32) ----------
__global__ void k_transpose_w(const float* __restrict__ W,
                              __hip_bfloat16* __restrict__ Wt) {
    int i = blockIdx.x * blockDim.x + threadIdx.x;
    if (i < IN_CH * NOUT) {
        int n = i >> 8, k = i & 255;
        Wt[i] = __float2bfloat16(W[k * NOUT + n]);
    }
}

// ---------- x = bf16(z) @ bf16(W) + fused attention scores ----------
// one wave = 16 rows x 128 cols, mfma_f32_16x16x32_bf16
// A: lane holds A[m=lane&15][k=quad*8+j];  B: lane holds B[k=quad*8+j][n=lane&15]
// C/D: col=lane&15, row=quad*4+reg
// epilogue also computes a_src[row][h]=dot(xrow_h, att_s[h]), a_dst likewise,
// reduced in-register (butterfly over the 16 m-lanes of each quad).
__global__ __launch_bounds__(256) void k_gemm_x(
        const float* __restrict__ z,
        const __hip_bfloat16* __restrict__ wt,
        const float* __restrict__ att_s,
        const float* __restrict__ att_d,
        __hip_bfloat16* __restrict__ x,
        float* __restrict__ a_src, float* __restrict__ a_dst, int nTiles) {
    int wid  = (blockIdx.x * blockDim.x + threadIdx.x) >> 6;
    if (wid >= nTiles) return;
    int lane = threadIdx.x & 63;
    int m = lane & 15, quad = lane >> 4;
    int rbase = wid * 16;
    const float* zp = z + (size_t)(rbase + m) * IN_CH + quad * 8;
    const short* wp = (const short*)wt + m * IN_CH + quad * 8;
    f32x4 acc[8] = {};
#pragma unroll
    for (int kb = 0; kb < 8; ++kb) {
        float4 f0 = *(const float4*)(zp + kb * 32);
        float4 f1 = *(const float4*)(zp + kb * 32 + 4);
        bf16x8 a;
        a[0] = f2bf(f0.x); a[1] = f2bf(f0.y); a[2] = f2bf(f0.z); a[3] = f2bf(f0.w);
        a[4] = f2bf(f1.x); a[5] = f2bf(f1.y); a[6] = f2bf(f1.z); a[7] = f2bf(f1.w);
#pragma unroll
        for (int n = 0; n < 8; ++n) {
            bf16x8 b = *(const bf16x8*)(wp + n * 16 * IN_CH + kb * 32);
            acc[n] = __builtin_amdgcn_mfma_f32_16x16x32_bf16(a, b, acc[n], 0, 0, 0);
        }
    }
    // store x (bf16)
#pragma unroll
    for (int n = 0; n < 8; ++n)
#pragma unroll
        for (int r = 0; r < 4; ++r) {
            int row = rbase + quad * 4 + r;
            x[(size_t)row * NOUT + n * 16 + m] = __float2bfloat16(acc[n][r]);
        }
    // fused attention scores
    float asv[8], adv[8];
#pragma unroll
    for (int n = 0; n < 8; ++n) {
        asv[n] = att_s[n * 16 + m];
        adv[n] = att_d[n * 16 + m];
    }
    float ps0[4] = {}, ps1[4] = {}, pd0[4] = {}, pd1[4] = {};
#pragma unroll
    for (int r = 0; r < 4; ++r)
#pragma unroll
        for (int n = 0; n < 4; ++n) {
            ps0[r] += acc[n][r] * asv[n];
            ps1[r] += acc[n + 4][r] * asv[n + 4];
            pd0[r] += acc[n][r] * adv[n];
            pd1[r] += acc[n + 4][r] * adv[n + 4];
        }
#pragma unroll
    for (int msk = 1; msk < 16; msk <<= 1)
#pragma unroll
        for (int r = 0; r < 4; ++r) {
            ps0[r] += __shfl_xor(ps0[r], msk);
            ps1[r] += __shfl_xor(ps1[r], msk);
            pd0[r] += __shfl_xor(pd0[r], msk);
            pd1[r] += __shfl_xor(pd1[r], msk);
        }
    if (m < 4) {
        int r = m;
        int row = rbase + quad * 4 + r;
        ((float2*)a_src)[row] = make_float2(ps0[r], ps1[r]);
        ((float2*)a_dst)[row] = make_float2(pd0[r], pd1[r]);
    }
}

// ---------- hist: count degree, record per-edge rank + e-values (coalesced) ----------
// ebuf[e] = { half2(e0,e1) bits, rank-within-dst }
__global__ void k_hist(const int* __restrict__ ei,
                       const float* __restrict__ a_src, const float* __restrict__ a_dst,
                       int* __restrict__ deg, int2* __restrict__ ebuf, int E) {
    int e = blockIdx.x * blockDim.x + threadIdx.x;
    if (e < E) {
        int s = ei[e], d = ei[E + e];
        float2 as = ((const float2*)a_src)[s];
        float2 ad = ((const float2*)a_dst)[d];
        float l0 = as.x + ad.x; l0 = (l0 > 0.f) ? l0 : NEG * l0;
        float l1 = as.y + ad.y; l1 = (l1 > 0.f) ? l1 : NEG * l1;
        __half2 h2;
        h2.x = __float2half(__expf(l0));
        h2.y = __float2half(__expf(l1));
        int pos = atomicAdd(&deg[d], 1);
        ebuf[e] = make_int2(*reinterpret_cast<int*>(&h2), pos);
    }
}

// block scans 2048 elements (256 thr x 8 items); +1 per node reserves self-loop slot
__global__ __launch_bounds__(256) void k_scan1(const int* __restrict__ deg,
                                               int* __restrict__ offs,
                                               int* __restrict__ bsum, int N) {
    __shared__ int sd[256];
    int t = threadIdx.x, b = blockIdx.x;
    int base = b * 2048 + t * 8;
    int it[8], s = 0;
#pragma unroll
    for (int j = 0; j < 8; ++j) {
        int idx = base + j;
        it[j] = (idx < N) ? (deg[idx] + 1) : 0;
        s += it[j];
    }
    sd[t] = s;
    __syncthreads();
    for (int off = 1; off < 256; off <<= 1) {
        int v = (t >= off) ? sd[t - off] : 0;
        __syncthreads();
        sd[t] += v;
        __syncthreads();
    }
    int excl = sd[t] - s;
    if (t == 255) bsum[b] = sd[255];
    int run = excl;
#pragma unroll
    for (int j = 0; j < 8; ++j) {
        int idx = base + j;
        if (idx < N) offs[idx] = run;
        run += it[j];
    }
}

__global__ void k_scan2(int* __restrict__ bsum, int* __restrict__ offs, int NB, int N) {
    int t = threadIdx.x;  // 64 threads
    int v = (t < NB) ? bsum[t] : 0;
    int orig = v;
    for (int off = 1; off < 64; off <<= 1) {
        int u = __shfl_up(v, off);
        if (t >= off) v += u;
    }
    if (t < NB) bsum[t] = v - orig;       // exclusive block offset
    if (t == 63) offs[N] = v;             // grand total = E + N
}

__global__ void k_scan3(int* __restrict__ offs, const int* __restrict__ bsum, int N) {
    int i = blockIdx.x * blockDim.x + threadIdx.x;
    if (i < N) offs[i] += bsum[i >> 11];
}

// ---------- scatter: atomic-free, gather-free for real edges ----------
// slot layout per dst: [offs[d]] = self-loop, [offs[d]+1+rank] = real edges
// epk[slot] = { half2(e0,e1) bits, src }
__global__ void k_scatter(const int* __restrict__ ei, const int* __restrict__ offs,
                          const int2* __restrict__ ebuf,
                          const float* __restrict__ a_src, const float* __restrict__ a_dst,
                          int2* __restrict__ epk, int E, int N) {
    int e = blockIdx.x * blockDim.x + threadIdx.x;
    if (e < E) {
        int s = ei[e], d = ei[E + e];
        int2 b = ebuf[e];
        epk[offs[d] + 1 + b.y] = make_int2(b.x, s);
    } else if (e < E + N) {
        int v = e - E;  // self-loop (coalesced loads)
        float2 as = ((const float2*)a_src)[v];
        float2 ad = ((const float2*)a_dst)[v];
        float l0 = as.x + ad.x; l0 = (l0 > 0.f) ? l0 : NEG * l0;
        float l1 = as.y + ad.y; l1 = (l1 > 0.f) ? l1 : NEG * l1;
        __half2 h2;
        h2.x = __float2half(__expf(l0));
        h2.y = __float2half(__expf(l1));
        epk[offs[v]] = make_int2(*reinterpret_cast<int*>(&h2), v);
    }
}

// ---------- main GAT aggregation: one wave per dst node, single fused pass ----------
// out_h = (sum_i e_i x_i) / (sum_i e_i)
__global__ __launch_bounds__(256) void k_gat_agg(
        const int2* __restrict__ epk, const int* __restrict__ offs,
        const __hip_bfloat16* __restrict__ x, const float* __restrict__ bias,
        float* __restrict__ out, int N) {
    int wid  = (blockIdx.x * blockDim.x + threadIdx.x) >> 6;
    if (wid >= N) return;
    int lane = threadIdx.x & 63;
    int beg = offs[wid], end = offs[wid + 1];
    int h = lane >> 5;   // lanes 0..31: head0 chans, 32..63: head1 chans
    const __hip_bfloat162* xv = (const __hip_bfloat162*)x;

    float ax[4] = {}, ay[4] = {}, dn[4] = {};   // 4 independent chains
    int i = beg;
    for (; i + 3 < end; i += 4) {
#pragma unroll
        for (int u = 0; u < 4; ++u) {
            int2 p = epk[i + u];
            __half2 h2 = *reinterpret_cast<__half2*>(&p.x);
            float2 ef = __half22float2(h2);
            float e = h ? ef.y : ef.x;
            __hip_bfloat162 f = xv[(size_t)p.y * 64 + lane];
            ax[u] += e * __bfloat162float(f.x);
            ay[u] += e * __bfloat162float(f.y);
            dn[u] += e;
        }
    }
    for (; i < end; ++i) {
        int2 p = epk[i];
        __half2 h2 = *reinterpret_cast<__half2*>(&p.x);
        float2 ef = __half22float2(h2);
        float e = h ? ef.y : ef.x;
        __hip_bfloat162 f = xv[(size_t)p.y * 64 + lane];
        ax[0] += e * __bfloat162float(f.x);
        ay[0] += e * __bfloat162float(f.y);
        dn[0] += e;
    }
    float inv = 1.f / ((dn[0] + dn[1]) + (dn[2] + dn[3]));
    float accx = ((ax[0] + ax[1]) + (ax[2] + ax[3])) * inv;
    float accy = ((ay[0] + ay[1]) + (ay[2] + ay[3])) * inv;
    // mean over heads: lane L<32 has head0 chans {2L,2L+1}; lane L+32 has head1 same chans
    float o0 = accx + __shfl_xor(accx, 32);
    float o1 = accy + __shfl_xor(accy, 32);
    if (lane < 32) {
        int c = 2 * lane;
        float2 o;
        o.x = 0.5f * o0 + bias[c];
        o.y = 0.5f * o1 + bias[c + 1];
        ((float2*)out)[(size_t)wid * 32 + lane] = o;
    }
}

extern "C" void kernel_launch(void* const* d_in, const int* in_sizes, int n_in,
                              void* d_out, int out_size, void* d_ws, size_t ws_size,
                              hipStream_t stream) {
    const float* z     = (const float*)d_in[0];
    const int*   ei    = (const int*)d_in[1];
    const float* W     = (const float*)d_in[2];
    const float* att_s = (const float*)d_in[3];
    const float* att_d = (const float*)d_in[4];
    const float* bias  = (const float*)d_in[5];
    float* out = (float*)d_out;

    const int N = in_sizes[0] / IN_CH;     // 100000
    const int E = in_sizes[1] / 2;         // 3200000
    const int Etot = E + N;

    // workspace carve-up (256B aligned)
    size_t off = 0;
    auto alloc = [&](size_t bytes) {
        void* p = (char*)d_ws + off;
        off += (bytes + 255) & ~(size_t)255;
        return p;
    };
    __hip_bfloat16* x    = (__hip_bfloat16*)alloc((size_t)N * NOUT * 2);
    __hip_bfloat16* Wt   = (__hip_bfloat16*)alloc((size_t)IN_CH * NOUT * 2);
    float* a_src         = (float*)alloc((size_t)N * 2 * 4);
    float* a_dst         = (float*)alloc((size_t)N * 2 * 4);
    int*   deg           = (int*)alloc((size_t)N * 4);
    int*   offs          = (int*)alloc((size_t)(N + 1) * 4);
    int*   bsum          = (int*)alloc(64 * 4);
    int2*  ebuf          = (int2*)alloc((size_t)E * 8);
    int2*  epk           = (int2*)alloc((size_t)Etot * 8);
    (void)ws_size;

    const int nTiles = N / 16;                 // 6250
    const int NB     = (N + 2047) / 2048;      // 49

    hipMemsetAsync(deg, 0, (size_t)N * 4, stream);
    k_transpose_w<<<(IN_CH * NOUT + 255) / 256, 256, 0, stream>>>(W, Wt);
    k_gemm_x<<<(nTiles + 3) / 4, 256, 0, stream>>>(z, Wt, att_s, att_d, x, a_src, a_dst, nTiles);
    k_hist<<<(E + 255) / 256, 256, 0, stream>>>(ei, a_src, a_dst, deg, ebuf, E);
    k_scan1<<<NB, 256, 0, stream>>>(deg, offs, bsum, N);
    k_scan2<<<1, 64, 0, stream>>>(bsum, offs, NB, N);
    k_scan3<<<(N + 255) / 256, 256, 0, stream>>>(offs, bsum, N);
    k_scatter<<<(Etot + 255) / 256, 256, 0, stream>>>(ei, offs, ebuf, a_src, a_dst, epk, E, N);
    k_gat_agg<<<(N + 3) / 4, 256, 0, stream>>>(epk, offs, x, bias, out, N);
}